// Round 7
// baseline (495.326 us; speedup 1.0000x reference)
//
#include <hip/hip_runtime.h>
#include <cmath>

#define TBL_SIZE (1u << 19)
#define TBL_MASK (TBL_SIZE - 1u)
#define PRIME1 2654435761u
#define PRIME2 805459861u
#define NUM_LEVELS 16
#define QLMAX 10
#define PPB_H 32    // points per 256-thr block, hashed path (8 lanes/point)
#define PPB_Q 128   // points per 256-thr block, quad path  (2 lanes/point)

struct Args {
    float s[NUM_LEVELS];
    uint32_t qoff[QLMAX];  // quad table base per level, in 16B units
    int qrp1[QLMAX];       // R+1 per quad level
};

typedef float v2f __attribute__((ext_vector_type(2)));

template<int CTRL>
__device__ __forceinline__ float dpp_add(float v) {
    int i = __builtin_bit_cast(int, v);
    int j = __builtin_amdgcn_mov_dpp(i, CTRL, 0xF, 0xF, true);
    return v + __builtin_bit_cast(float, j);
}

__device__ __forceinline__ uint32_t f2bf(float f) {  // f32->bf16 RNE (no NaN in data)
    uint32_t u = __builtin_bit_cast(uint32_t, f);
    return (u + 0x7FFFu + ((u >> 16) & 1u)) >> 16;
}
__device__ __forceinline__ float bflo(uint32_t v) { return __builtin_bit_cast(float, v << 16); }
__device__ __forceinline__ float bfhi(uint32_t v) { return __builtin_bit_cast(float, v & 0xFFFF0000u); }

// Pack hashed levels [QL, QL+NBF) into bf16-pair entries (4B) in ws.
__global__ __launch_bounds__(256) void cvt_hashed_kernel(
    const float* __restrict__ table, uint32_t* __restrict__ dst, int QL, int nentries)
{
    int gid = blockIdx.x * 256 + (int)threadIdx.x;
    if (gid >= nentries) return;
    float2 e = reinterpret_cast<const float2*>(table)[((size_t)QL << 19) + gid];
    dst[gid] = f2bf(e.x) | (f2bf(e.y) << 16);
}

// Build dense quad table for one level: quad[x][y0][z0] (16B) = bf16 pairs at
// (y0,z0),(y0,z0+1),(y0+1,z0),(y0+1,z0+1). 2x2 quad tile per thread: 9 gathers / 4 quads.
__global__ __launch_bounds__(256) void build_quads_kernel(
    const float* __restrict__ table, uint4* __restrict__ qt,
    uint32_t qoff, int R, int level, int T, int ntiles)
{
    int id = blockIdx.x * 256 + (int)threadIdx.x;
    if (id >= ntiles) return;
    int t2 = T * T;
    int xp = id / t2; int rem = id - xp * t2;
    int ty = rem / T; int tz = rem - ty * T;
    int y0 = ty * 2, z0 = tz * 2;

    const float2* tb = reinterpret_cast<const float2*>(table) + ((size_t)level << 19);
    uint32_t vals[3][3];
    #pragma unroll
    for (int dy = 0; dy < 3; ++dy)
        #pragma unroll
        for (int dz = 0; dz < 3; ++dz) {
            uint32_t h = (uint32_t)xp ^ ((uint32_t)(y0 + dy) * PRIME1)
                                      ^ ((uint32_t)(z0 + dz) * PRIME2);
            float2 e = tb[h & TBL_MASK];
            vals[dy][dz] = f2bf(e.x) | (f2bf(e.y) << 16);
        }
    int Rp1 = R + 1;
    #pragma unroll
    for (int a = 0; a < 2; ++a)
        #pragma unroll
        for (int c = 0; c < 2; ++c) {
            int Y = y0 + a, Z = z0 + c;
            if (Y <= R && Z <= R) {
                uint4 q;
                q.x = vals[a][c];     q.y = vals[a][c + 1];
                q.z = vals[a + 1][c]; q.w = vals[a + 1][c + 1];
                qt[qoff + ((size_t)xp * Rp1 + Y) * Rp1 + Z] = q;
            }
        }
}

// Main: hashed levels [QL,16) corner-per-lane (8 req/pt-level, bf16 if converted);
// quad levels [0,QL) plane-per-lane (2x 16B req/pt-level). XCD-affine hashed split.
__global__ __launch_bounds__(256) void HashEncoding_88837103551034_kernel(
    const float* __restrict__ x,
    const float* __restrict__ table,
    const uint32_t* __restrict__ ws32,   // ws base: quads (16B units), bf16 hashed at bfbase
    float* __restrict__ out,
    int npoints, int CH, int CHq, int perXcdHard, int hardTotal, int quadTotal,
    int QL, int NBF, uint32_t bfbase,    // bfbase in 4B units
    Args args)
{
    int b = blockIdx.x; int xcd = b & 7; int sb = b >> 3;
    int t = (int)threadIdx.x;

    if (sb < perXcdHard) {
        // ---- hashed path ----
        int g = xcd * perXcdHard + sb;
        if (g >= hardTotal) return;
        int li = g / CH; int level = QL + li; int chunk = g - li * CH;
        int corner = t & 7;
        int n = chunk * PPB_H + (t >> 3);
        if (n >= npoints) return;

        float x0 = x[(size_t)n * 3 + 0] * 0.5f + 0.5f;
        float x1 = x[(size_t)n * 3 + 1] * 0.5f + 0.5f;
        float x2 = x[(size_t)n * 3 + 2] * 0.5f + 0.5f;
        float sl = args.s[level];
        float sx = x0 * sl, sy = x1 * sl, sz = x2 * sl;
        float fx = floorf(sx), fy = floorf(sy), fz = floorf(sz);
        float ox = sx - fx, oy = sy - fy, oz = sz - fz;
        int bx = (corner >> 2) & 1, by = (corner >> 1) & 1, bz = corner & 1;

        // ceil==floor+1 except integral coords, where the ceil-corner weight is 0.
        uint32_t h = (uint32_t)((int)fx + bx)
                   ^ ((uint32_t)((int)fy + by) * PRIME1)
                   ^ ((uint32_t)((int)fz + bz) * PRIME2);
        uint32_t idx = h & TBL_MASK;

        float f0, f1;
        if (li < NBF) {
            uint32_t v = ws32[bfbase + ((size_t)li << 19) + idx];
            f0 = bflo(v); f1 = bfhi(v);
        } else {
            float2 f = reinterpret_cast<const float2*>(table)[((size_t)level << 19) + idx];
            f0 = f.x; f1 = f.y;
        }
        float w = (bx ? ox : 1.f - ox) * (by ? oy : 1.f - oy) * (bz ? oz : 1.f - oz);
        float e0 = f0 * w, e1 = f1 * w;
        e0 = dpp_add<0xB1>(e0);  e1 = dpp_add<0xB1>(e1);   // xor1
        e0 = dpp_add<0x4E>(e0);  e1 = dpp_add<0x4E>(e1);   // xor2
        e0 = dpp_add<0x141>(e0); e1 = dpp_add<0x141>(e1);  // half-row mirror (0<-7)
        if (corner == 0) {
            v2f res; res.x = e0; res.y = e1;
            __builtin_nontemporal_store(res, (v2f*)(out + (size_t)n * 32 + level * 2));
        }
    } else {
        // ---- quad path ----
        int g = (sb - perXcdHard) * 8 + xcd;
        if (g >= quadTotal) return;
        int li = g / CHq; int level = li; int chunk = g - li * CHq;
        int bx = t & 1;
        int n = chunk * PPB_Q + (t >> 1);
        if (n >= npoints) return;

        float x0 = x[(size_t)n * 3 + 0] * 0.5f + 0.5f;
        float x1 = x[(size_t)n * 3 + 1] * 0.5f + 0.5f;
        float x2 = x[(size_t)n * 3 + 2] * 0.5f + 0.5f;
        float sl = args.s[level];
        float sx = x0 * sl, sy = x1 * sl, sz = x2 * sl;
        float fx = floorf(sx), fy = floorf(sy), fz = floorf(sz);
        float ox = sx - fx, oy = sy - fy, oz = sz - fz;

        int xi = (int)fx + bx, yi = (int)fy, zi = (int)fz;
        int Rp1 = args.qrp1[level];
        const uint4* qt = reinterpret_cast<const uint4*>(ws32);
        uint4 q = qt[args.qoff[level] + ((size_t)xi * Rp1 + yi) * Rp1 + zi];

        float wx = bx ? ox : 1.f - ox;
        float wy0 = 1.f - oy, wy1 = oy, wz0 = 1.f - oz, wz1 = oz;
        float e0 = wx * (wy0 * (wz0 * bflo(q.x) + wz1 * bflo(q.y))
                       + wy1 * (wz0 * bflo(q.z) + wz1 * bflo(q.w)));
        float e1 = wx * (wy0 * (wz0 * bfhi(q.x) + wz1 * bfhi(q.y))
                       + wy1 * (wz0 * bfhi(q.z) + wz1 * bfhi(q.w)));
        e0 = dpp_add<0xB1>(e0);  e1 = dpp_add<0xB1>(e1);   // xor1: lane pair sum
        if (bx == 0) {
            v2f res; res.x = e0; res.y = e1;
            __builtin_nontemporal_store(res, (v2f*)(out + (size_t)n * 32 + level * 2));
        }
    }
}

extern "C" void kernel_launch(void* const* d_in, const int* in_sizes, int n_in,
                              void* d_out, int out_size, void* d_ws, size_t ws_size,
                              hipStream_t stream) {
    const float* x = (const float*)d_in[0];
    const float* table = (const float*)d_in[1];
    float* out = (float*)d_out;
    int npoints = in_sizes[0] / 3;

    Args args;
    double growth = std::exp((std::log(1024.0) - std::log(16.0)) / 15.0);
    for (int l = 0; l < NUM_LEVELS; ++l)
        args.s[l] = (float)std::floor(16.0 * std::pow(growth, (double)l));
    for (int l = 0; l < QLMAX; ++l) { args.qoff[l] = 0; args.qrp1[l] = 1; }

    // Tier quad levels into ws (16B per cell), greedily from level 0.
    uint64_t cum16 = 0; int QL = 0;
    int Rl[QLMAX], Tl[QLMAX], ntl[QLMAX];
    for (int l = 0; l < QLMAX && l < NUM_LEVELS; ++l) {
        int R = (int)args.s[l];
        uint64_t ent = (uint64_t)(R + 2) * (R + 1) * (R + 1);
        if ((cum16 + ent) * 16 > ws_size) break;
        args.qoff[l] = (uint32_t)cum16; args.qrp1[l] = R + 1;
        Rl[l] = R; Tl[l] = (R + 2) >> 1;
        ntl[l] = (R + 2) * Tl[l] * Tl[l];
        cum16 += ent; QL = l + 1;
    }
    // bf16-pack as many hashed levels as fit in the remainder.
    uint64_t used = cum16 * 16;
    int NBF = 0; uint32_t bfbase = (uint32_t)(used / 4);
    if (ws_size > used) {
        uint64_t remain = ws_size - used;
        NBF = (int)(remain / ((uint64_t)TBL_SIZE * 4));
        if (NBF > NUM_LEVELS - QL) NBF = NUM_LEVELS - QL;
    }

    uint32_t* ws32 = (uint32_t*)d_ws;

    if (NBF > 0) {
        int nent = NBF << 19;
        cvt_hashed_kernel<<<(nent + 255) / 256, 256, 0, stream>>>(
            table, ws32 + bfbase, QL, nent);
    }
    for (int l = 0; l < QL; ++l) {
        build_quads_kernel<<<(ntl[l] + 255) / 256, 256, 0, stream>>>(
            table, (uint4*)d_ws, args.qoff[l], Rl[l], l, Tl[l], ntl[l]);
    }

    int CH  = (npoints + PPB_H - 1) / PPB_H;
    int CHq = (npoints + PPB_Q - 1) / PPB_Q;
    int hardTotal = (NUM_LEVELS - QL) * CH;
    int quadTotal = QL * CHq;
    int perXcdHard = (hardTotal + 7) / 8;
    int perXcdQuad = (quadTotal + 7) / 8;
    int grid = 8 * (perXcdHard + perXcdQuad);

    HashEncoding_88837103551034_kernel<<<grid, 256, 0, stream>>>(
        x, table, ws32, out, npoints, CH, CHq, perXcdHard, hardTotal, quadTotal,
        QL, NBF, bfbase, args);
}

// Round 8
// 272.068 us; speedup vs baseline: 1.8206x; 1.8206x over previous
//
#include <hip/hip_runtime.h>
#include <cmath>

#define TBL_SIZE (1u << 19)
#define TBL_MASK (TBL_SIZE - 1u)
#define PRIME1 2654435761u
#define PRIME2 805459861u
#define NUM_LEVELS 16
#define DLMAX 7       // dense levels 0..6 (level-6 table 2.6MB = L2-class; beyond that dense is cache-ineffective)
#define PPB 32        // points per 256-thread block (8 lanes per point)

struct Args {
    float s[NUM_LEVELS];
    uint32_t doff[DLMAX];  // dense table base per level (4B units)
    int ddim[DLMAX];       // R+2 per dense level
};

typedef float v2f __attribute__((ext_vector_type(2)));

template<int CTRL>
__device__ __forceinline__ float dpp_add(float v) {
    int i = __builtin_bit_cast(int, v);
    int j = __builtin_amdgcn_mov_dpp(i, CTRL, 0xF, 0xF, true);
    return v + __builtin_bit_cast(float, j);
}

__device__ __forceinline__ uint32_t f2bf(float f) {  // f32->bf16 RNE (no NaN in data)
    uint32_t u = __builtin_bit_cast(uint32_t, f);
    return (u + 0x7FFFu + ((u >> 16) & 1u)) >> 16;
}
__device__ __forceinline__ float bflo(uint32_t v) { return __builtin_bit_cast(float, v << 16); }
__device__ __forceinline__ float bfhi(uint32_t v) { return __builtin_bit_cast(float, v & 0xFFFF0000u); }

// Pack hashed levels [DL, DL+NBF) into bf16-pair entries (4B) in ws.
__global__ __launch_bounds__(256) void cvt_hashed_kernel(
    const float* __restrict__ table, uint32_t* __restrict__ dst, int DL, int nentries)
{
    int gid = blockIdx.x * 256 + (int)threadIdx.x;
    if (gid >= nentries) return;
    float2 e = reinterpret_cast<const float2*>(table)[((size_t)DL << 19) + gid];
    dst[gid] = f2bf(e.x) | (f2bf(e.y) << 16);
}

// Dense spatial table for one level: entry[(x*dim+y)*dim+z] = bf16 pair at integer
// coord (x,y,z), dim=R+2 (covers the weight-0 phantom corners at R+1 in-bounds).
__global__ __launch_bounds__(256) void build_dense_kernel(
    const float* __restrict__ table, uint32_t* __restrict__ dst,
    uint32_t doff, int dim, int level, int nentries)
{
    int id = blockIdx.x * 256 + (int)threadIdx.x;
    if (id >= nentries) return;
    int d2 = dim * dim;
    int xp = id / d2; int rem = id - xp * d2;
    int yp = rem / dim; int zp = rem - yp * dim;
    uint32_t h = (uint32_t)xp ^ ((uint32_t)yp * PRIME1) ^ ((uint32_t)zp * PRIME2);
    float2 e = reinterpret_cast<const float2*>(table)[((size_t)level << 19) + (h & TBL_MASK)];
    dst[doff + id] = f2bf(e.x) | (f2bf(e.y) << 16);
}

// Main. Corner-per-lane everywhere (8 lanes per point-level).
//  hard pool (contiguous per XCD): [dense L6 if DL==7] + hashed levels DL..15.
//  easy pool (striped): dense levels 0..min(DL,6)-1.
__global__ __launch_bounds__(256) void HashEncoding_88837103551034_kernel(
    const float* __restrict__ x,
    const float* __restrict__ table,
    const uint32_t* __restrict__ ws32,
    float* __restrict__ out,
    int npoints, int CH, int perXcdHard, int hardTotal, int easyTotal,
    int DL, int NBF, uint32_t bfbase,
    Args args)
{
    int b = blockIdx.x; int xcd = b & 7; int sb = b >> 3;
    int t = (int)threadIdx.x;
    int corner = t & 7;

    int level, chunk;
    if (sb < perXcdHard) {
        int g = xcd * perXcdHard + sb;
        if (g >= hardTotal) return;
        int li = g / CH; chunk = g - li * CH;
        if (DL == DLMAX) level = (li == 0) ? 6 : 6 + li;   // unit0 = dense L6, then hashed 7..15
        else             level = DL + li;                   // all hashed
    } else {
        int g = (sb - perXcdHard) * 8 + xcd;
        if (g >= easyTotal) return;
        int li = g / CH; chunk = g - li * CH;
        level = li;                                         // dense 0..elvls-1
    }

    int n = chunk * PPB + (t >> 3);
    if (n >= npoints) return;

    float x0 = x[(size_t)n * 3 + 0] * 0.5f + 0.5f;
    float x1 = x[(size_t)n * 3 + 1] * 0.5f + 0.5f;
    float x2 = x[(size_t)n * 3 + 2] * 0.5f + 0.5f;
    float sl = args.s[level];
    float sx = x0 * sl, sy = x1 * sl, sz = x2 * sl;
    float fx = floorf(sx), fy = floorf(sy), fz = floorf(sz);
    float ox = sx - fx, oy = sy - fy, oz = sz - fz;
    int bx = (corner >> 2) & 1, by = (corner >> 1) & 1, bz = corner & 1;

    float f0, f1;
    if (level < DL) {
        // dense: z-adjacent corner lanes share a cache line -> TCP merges.
        int dim = args.ddim[level];
        int idx = (((int)fx + bx) * dim + (int)fy + by) * dim + (int)fz + bz;
        uint32_t v = ws32[args.doff[level] + idx];
        f0 = bflo(v); f1 = bfhi(v);
    } else {
        // hashed: ceil==floor+1 except integral coords (weight-0 there).
        uint32_t h = (uint32_t)((int)fx + bx)
                   ^ ((uint32_t)((int)fy + by) * PRIME1)
                   ^ ((uint32_t)((int)fz + bz) * PRIME2);
        uint32_t idx = h & TBL_MASK;
        int li = level - DL;
        if (li < NBF) {
            uint32_t v = ws32[bfbase + ((size_t)li << 19) + idx];
            f0 = bflo(v); f1 = bfhi(v);
        } else {
            float2 f = reinterpret_cast<const float2*>(table)[((size_t)level << 19) + idx];
            f0 = f.x; f1 = f.y;
        }
    }

    float w = (bx ? ox : 1.f - ox) * (by ? oy : 1.f - oy) * (bz ? oz : 1.f - oz);
    float e0 = f0 * w, e1 = f1 * w;
    e0 = dpp_add<0xB1>(e0);  e1 = dpp_add<0xB1>(e1);   // xor1
    e0 = dpp_add<0x4E>(e0);  e1 = dpp_add<0x4E>(e1);   // xor2
    e0 = dpp_add<0x141>(e0); e1 = dpp_add<0x141>(e1);  // half-row mirror (0<-7)
    if (corner == 0) {
        v2f res; res.x = e0; res.y = e1;
        __builtin_nontemporal_store(res, (v2f*)(out + (size_t)n * 32 + level * 2));
    }
}

extern "C" void kernel_launch(void* const* d_in, const int* in_sizes, int n_in,
                              void* d_out, int out_size, void* d_ws, size_t ws_size,
                              hipStream_t stream) {
    const float* x = (const float*)d_in[0];
    const float* table = (const float*)d_in[1];
    float* out = (float*)d_out;
    int npoints = in_sizes[0] / 3;

    Args args;
    double growth = std::exp((std::log(1024.0) - std::log(16.0)) / 15.0);
    for (int l = 0; l < NUM_LEVELS; ++l)
        args.s[l] = (float)std::floor(16.0 * std::pow(growth, (double)l));
    for (int l = 0; l < DLMAX; ++l) { args.doff[l] = 0; args.ddim[l] = 1; }

    // Dense levels 0..6 only (cache-effective); cap by ws.
    uint64_t cum4 = 0; int DL = 0;
    int nent_d[DLMAX];
    for (int l = 0; l < DLMAX; ++l) {
        int dim = (int)args.s[l] + 2;
        uint64_t ent = (uint64_t)dim * dim * dim;
        if ((cum4 + ent) * 4 > ws_size) break;
        args.doff[l] = (uint32_t)cum4; args.ddim[l] = dim;
        nent_d[l] = (int)ent;
        cum4 += ent; DL = l + 1;
    }
    // bf16-pack hashed levels DL..15 into the remainder.
    uint64_t used = cum4 * 4;
    int NBF = 0; uint32_t bfbase = (uint32_t)cum4;
    if (ws_size > used) {
        NBF = (int)((ws_size - used) / ((uint64_t)TBL_SIZE * 4));
        if (NBF > NUM_LEVELS - DL) NBF = NUM_LEVELS - DL;
    }

    uint32_t* ws32 = (uint32_t*)d_ws;
    if (NBF > 0) {
        int nent = NBF << 19;
        cvt_hashed_kernel<<<(nent + 255) / 256, 256, 0, stream>>>(table, ws32 + bfbase, DL, nent);
    }
    for (int l = 0; l < DL; ++l) {
        build_dense_kernel<<<(nent_d[l] + 255) / 256, 256, 0, stream>>>(
            table, ws32, args.doff[l], args.ddim[l], l, nent_d[l]);
    }

    int CH = (npoints + PPB - 1) / PPB;
    int elvls = (DL > 6) ? 6 : DL;                      // striped dense levels
    int hardUnits = (NUM_LEVELS - DL) + (DL == DLMAX ? 1 : 0);
    int hardTotal = hardUnits * CH;
    int easyTotal = elvls * CH;
    int perXcdHard = (hardTotal + 7) / 8;
    int perXcdEasy = (easyTotal + 7) / 8;
    int grid = 8 * (perXcdHard + perXcdEasy);

    HashEncoding_88837103551034_kernel<<<grid, 256, 0, stream>>>(
        x, table, ws32, out, npoints, CH, perXcdHard, hardTotal, easyTotal,
        DL, NBF, bfbase, args);
}